// Round 3
// baseline (1026.127 us; speedup 1.0000x reference)
//
#include <hip/hip_runtime.h>

#define N_NODES 200000
#define N_EDGES 3200000
#define N_GRAPHS 1024
#define HD 16
#define ALPHA_ 0.2f

#define BNODES 256                 // nodes per bucket (dst >> 8)
#define NBUCK 782                  // ceil(N_NODES/256)
#define CHUNKA 4096                // edges per pass-A block
#define NBLKA 782                  // ceil(N_EDGES/CHUNKA)

// ---------- pass A: per-block histogram over buckets (LDS atomics only) ----------
__global__ __launch_bounds__(256) void hist_kernel(const int* __restrict__ dst,
                                                   int* __restrict__ blkhist) {
    __shared__ int hist[NBUCK];
    int t = threadIdx.x;
    for (int i = t; i < NBUCK; i += 256) hist[i] = 0;
    __syncthreads();
    int e0 = blockIdx.x * CHUNKA;
    int e1 = min(e0 + CHUNKA, N_EDGES);
    for (int e = e0 + t; e < e1; e += 256)
        atomicAdd(&hist[dst[e] >> 8], 1);
    __syncthreads();
    int* out = blkhist + (size_t)blockIdx.x * NBUCK;
    for (int i = t; i < NBUCK; i += 256) out[i] = hist[i];
}

// scan each bucket's column across blocks (in place -> exclusive), totals -> bstart
__global__ __launch_bounds__(256) void scanA_kernel(int* __restrict__ blkhist,
                                                    int* __restrict__ bstart) {
    __shared__ int s[256];
    int u = blockIdx.x, t = threadIdx.x;
    int v[4];
    int sum = 0;
#pragma unroll
    for (int i = 0; i < 4; ++i) {
        int j = t * 4 + i;
        v[i] = (j < NBLKA) ? blkhist[(size_t)j * NBUCK + u] : 0;
        sum += v[i];
    }
    s[t] = sum;
    __syncthreads();
    for (int off = 1; off < 256; off <<= 1) {
        int x = (t >= off) ? s[t - off] : 0;
        __syncthreads();
        s[t] += x;
        __syncthreads();
    }
    int run = s[t] - sum;
#pragma unroll
    for (int i = 0; i < 4; ++i) {
        int j = t * 4 + i;
        if (j < NBLKA) blkhist[(size_t)j * NBUCK + u] = run;
        run += v[i];
    }
    if (t == 255) bstart[u] = s[255];
}

// exclusive scan over bucket totals (single block)
__global__ __launch_bounds__(256) void scanB_kernel(int* __restrict__ bstart) {
    __shared__ int s[256];
    int t = threadIdx.x;
    int v[4];
    int sum = 0;
#pragma unroll
    for (int i = 0; i < 4; ++i) {
        int j = t * 4 + i;
        v[i] = (j < NBUCK) ? bstart[j] : 0;
        sum += v[i];
    }
    s[t] = sum;
    __syncthreads();
    for (int off = 1; off < 256; off <<= 1) {
        int x = (t >= off) ? s[t - off] : 0;
        __syncthreads();
        s[t] += x;
        __syncthreads();
    }
    int run = s[t] - sum;
#pragma unroll
    for (int i = 0; i < 4; ++i) {
        int j = t * 4 + i;
        if (j < NBUCK) bstart[j] = run;
        run += v[i];
    }
    if (t == 255) bstart[NBUCK] = s[255];
}

// scatter edges into bucket regions; entry = (ea:32 | dlow:8 | src:18)
__global__ __launch_bounds__(256) void scatter_kernel(const int* __restrict__ src,
                                                      const int* __restrict__ dst,
                                                      const float* __restrict__ ea,
                                                      const int* __restrict__ blkhist,
                                                      const int* __restrict__ bstart,
                                                      unsigned long long* __restrict__ bucketed) {
    __shared__ int cursor[NBUCK];
    int t = threadIdx.x;
    const int* bo = blkhist + (size_t)blockIdx.x * NBUCK;
    for (int i = t; i < NBUCK; i += 256) cursor[i] = bstart[i] + bo[i];
    __syncthreads();
    int e0 = blockIdx.x * CHUNKA;
    int e1 = min(e0 + CHUNKA, N_EDGES);
    for (int e = e0 + t; e < e1; e += 256) {
        int d = dst[e];
        int u = d >> 8;
        int pos = atomicAdd(&cursor[u], 1);   // LDS atomic
        unsigned long long ent = ((unsigned long long)__float_as_uint(ea[e]) << 32)
                               | (unsigned)(src[e] | ((d & 255) << 18));
        bucketed[pos] = ent;
    }
}

// weighted degree -> dinv, block per bucket, LDS float atomics
__global__ __launch_bounds__(256) void dinvB_kernel(const unsigned long long* __restrict__ bucketed,
                                                    const int* __restrict__ bstart,
                                                    float* __restrict__ dinv) {
    __shared__ float wdeg[BNODES];
    int u = blockIdx.x, t = threadIdx.x;
    wdeg[t] = 0.f;
    __syncthreads();
    int b0 = bstart[u], b1 = bstart[u + 1];
    for (int i = b0 + t; i < b1; i += 256) {
        unsigned long long ent = bucketed[i];
        int dlow = (int)((ent >> 18) & 255u);
        atomicAdd(&wdeg[dlow], __uint_as_float((unsigned)(ent >> 32)));
    }
    __syncthreads();
    int n = u * BNODES + t;
    if (n < N_NODES) dinv[n] = rsqrtf(wdeg[t] + 1.0f);
}

// rewrite ea -> w = dinv[s]*ea*dinv[d] in place
__global__ __launch_bounds__(256) void wnorm_kernel(unsigned long long* __restrict__ bucketed,
                                                    const int* __restrict__ bstart,
                                                    const float* __restrict__ dinv) {
    __shared__ float sdinv[BNODES];
    int u = blockIdx.x, t = threadIdx.x;
    int n = u * BNODES + t;
    sdinv[t] = (n < N_NODES) ? dinv[n] : 0.f;
    __syncthreads();
    int b0 = bstart[u], b1 = bstart[u + 1];
    for (int i = b0 + t; i < b1; i += 256) {
        unsigned long long ent = bucketed[i];
        int s = (int)(ent & 0x3ffffu);
        int dlow = (int)((ent >> 18) & 255u);
        float eav = __uint_as_float((unsigned)(ent >> 32));
        float w = dinv[s] * eav * sdinv[dlow];
        bucketed[i] = ((unsigned long long)__float_as_uint(w) << 32)
                    | (unsigned)(ent & 0x03ffffffu);
    }
}

// layer 0 (rank-1: hW = x * cw0^T): scalar aggregation + outer product + linear
__global__ __launch_bounds__(256) void agg0_kernel(const unsigned long long* __restrict__ bucketed,
                                                   const int* __restrict__ bstart,
                                                   const float* __restrict__ x,
                                                   const float* __restrict__ dinv,
                                                   const float* __restrict__ cw0,
                                                   const float* __restrict__ cb0,
                                                   const float* __restrict__ lw0,
                                                   const float* __restrict__ lb0,
                                                   float* __restrict__ h) {
    __shared__ float acc[BNODES];
    __shared__ float sW[256], scw[16], scb[16], slb[16];
    int u = blockIdx.x, t = threadIdx.x;
    sW[t] = lw0[t];
    if (t < 16) { scw[t] = cw0[t]; scb[t] = cb0[t]; slb[t] = lb0[t]; }
    acc[t] = 0.f;
    __syncthreads();
    int b0 = bstart[u], b1 = bstart[u + 1];
    for (int i = b0 + t; i < b1; i += 256) {
        unsigned long long ent = bucketed[i];
        int s = (int)(ent & 0x3ffffu);
        int dlow = (int)((ent >> 18) & 255u);
        float w = __uint_as_float((unsigned)(ent >> 32));
        atomicAdd(&acc[dlow], w * x[s]);
    }
    __syncthreads();
    int n = u * BNODES + t;
    if (n >= N_NODES) return;
    float dn = dinv[n];
    float base = acc[t] + dn * dn * x[n];
    float a[16];
#pragma unroll
    for (int j = 0; j < 16; ++j) a[j] = fmaxf(base * scw[j] + scb[j], 0.f);
    float o[16];
#pragma unroll
    for (int j = 0; j < 16; ++j) o[j] = slb[j];
#pragma unroll
    for (int k = 0; k < 16; ++k)
#pragma unroll
        for (int j = 0; j < 16; ++j) o[j] += a[k] * sW[k * 16 + j];
    float4* op = (float4*)(h + (size_t)n * HD);
    op[0] = make_float4(o[0], o[1], o[2], o[3]);
    op[1] = make_float4(o[4], o[5], o[6], o[7]);
    op[2] = make_float4(o[8], o[9], o[10], o[11]);
    op[3] = make_float4(o[12], o[13], o[14], o[15]);
}

// hW = h @ W (16x16)
__global__ __launch_bounds__(256) void mat16_kernel(const float* __restrict__ in,
                                                    const float* __restrict__ W,
                                                    float* __restrict__ out) {
    __shared__ float sW[256];
    sW[threadIdx.x] = W[threadIdx.x];
    __syncthreads();
    int n = blockIdx.x * blockDim.x + threadIdx.x;
    if (n >= N_NODES) return;
    const float4* inr = (const float4*)(in + (size_t)n * HD);
    float4 r0 = inr[0], r1 = inr[1], r2 = inr[2], r3 = inr[3];
    float a[16] = {r0.x, r0.y, r0.z, r0.w, r1.x, r1.y, r1.z, r1.w,
                   r2.x, r2.y, r2.z, r2.w, r3.x, r3.y, r3.z, r3.w};
    float acc[16];
#pragma unroll
    for (int j = 0; j < 16; ++j) acc[j] = 0.f;
#pragma unroll
    for (int k = 0; k < 16; ++k)
#pragma unroll
        for (int j = 0; j < 16; ++j) acc[j] += a[k] * sW[k * 16 + j];
    float4* o = (float4*)(out + (size_t)n * HD);
    o[0] = make_float4(acc[0], acc[1], acc[2], acc[3]);
    o[1] = make_float4(acc[4], acc[5], acc[6], acc[7]);
    o[2] = make_float4(acc[8], acc[9], acc[10], acc[11]);
    o[3] = make_float4(acc[12], acc[13], acc[14], acc[15]);
}

// layers 1,2: block per bucket; stream edges -> LDS acc[256][16]; fused epilogue
__global__ __launch_bounds__(256) void agg_kernel(const unsigned long long* __restrict__ bucketed,
                                                  const int* __restrict__ bstart,
                                                  const float* __restrict__ hW,
                                                  const float* __restrict__ dinv,
                                                  const float* __restrict__ cb_l,
                                                  const float* __restrict__ lw_l,
                                                  const float* __restrict__ lb_l,
                                                  float* __restrict__ h) {
    __shared__ float acc[BNODES * 16];   // 16 KB
    __shared__ float sW[256], scb[16], sb[16];
    int t = threadIdx.x;
    int u = blockIdx.x;
    sW[t] = lw_l[t];
    if (t < 16) { scb[t] = cb_l[t]; sb[t] = lb_l[t]; }
    for (int i = t; i < BNODES * 16; i += 256) acc[i] = 0.f;
    __syncthreads();
    int b0 = bstart[u], b1 = bstart[u + 1];
    int j = t & 15;    // feature lane
    int es = t >> 4;   // edge slot 0..15
    for (int i = b0 + es; i < b1; i += 16) {
        unsigned long long ent = bucketed[i];   // broadcast across 16 lanes
        int s = (int)(ent & 0x3ffffu);
        int dlow = (int)((ent >> 18) & 255u);
        float w = __uint_as_float((unsigned)(ent >> 32));
        atomicAdd(&acc[dlow * 16 + j], w * hW[(size_t)s * 16 + j]);
    }
    __syncthreads();
    int bl = (t & 63) & ~15;
    for (int l0 = 0; l0 < BNODES; l0 += 16) {
        int l = l0 + (t >> 4);
        int n = u * BNODES + l;
        float a = 0.f;
        if (n < N_NODES) {
            float dn = dinv[n];
            a = fmaxf(acc[l * 16 + j] + dn * dn * hW[(size_t)n * 16 + j] + scb[j], 0.f);
        }
        float o = sb[j];
#pragma unroll
        for (int k = 0; k < 16; ++k)
            o += __shfl(a, bl + k, 64) * sW[k * 16 + j];
        if (n < N_NODES) h[(size_t)n * 16 + j] = o;
    }
}

// segmented pooling over sorted batch
#define POOL_RUN 32
__global__ __launch_bounds__(256) void pool_kernel(const float* __restrict__ h,
                                                   const int* __restrict__ batch,
                                                   float* __restrict__ num,
                                                   float* __restrict__ den) {
    int t = threadIdx.x;
    int tg = t >> 4, j = t & 15;
    int n_start = blockIdx.x * (16 * POOL_RUN) + tg * POOL_RUN;
    float accn = 0.f, accd = 0.f;
    int cur = -1;
    for (int k = 0; k < POOL_RUN; ++k) {
        int n = n_start + k;
        if (n >= N_NODES) break;
        int g = batch[n];
        if (g != cur) {
            if (cur >= 0) {
                atomicAdd(&num[cur * HD + j], accn);
                atomicAdd(&den[cur * HD + j], accd);
            }
            cur = g;
            accn = 0.f;
            accd = 0.f;
        }
        float v = h[(size_t)n * HD + j];
        float s = expf(ALPHA_ * v);
        accn += v * s;
        accd += s;
    }
    if (cur >= 0) {
        atomicAdd(&num[cur * HD + j], accn);
        atomicAdd(&den[cur * HD + j], accd);
    }
}

__global__ __launch_bounds__(64) void final_kernel(const float* __restrict__ num,
                                                   const float* __restrict__ den,
                                                   const float* __restrict__ w1,
                                                   const float* __restrict__ b1,
                                                   const float* __restrict__ w2,
                                                   const float* __restrict__ b2,
                                                   const float* __restrict__ w3,
                                                   const float* __restrict__ b3,
                                                   float* __restrict__ out) {
    int g = blockIdx.x * blockDim.x + threadIdx.x;
    if (g >= N_GRAPHS) return;
    float p[16];
#pragma unroll
    for (int j = 0; j < 16; ++j) p[j] = num[g * HD + j] / den[g * HD + j];
    float t1[16];
#pragma unroll
    for (int j = 0; j < 16; ++j) {
        float acc = b1[j];
#pragma unroll
        for (int k = 0; k < 16; ++k) acc += p[k] * w1[k * 16 + j];
        t1[j] = fmaxf(acc, 0.f);
    }
    float t2[16];
#pragma unroll
    for (int j = 0; j < 16; ++j) {
        float acc = b2[j];
#pragma unroll
        for (int k = 0; k < 16; ++k) acc += t1[k] * w2[k * 16 + j];
        t2[j] = fmaxf(acc, 0.f);
    }
    float o = b3[0];
#pragma unroll
    for (int k = 0; k < 16; ++k) o += t2[k] * w3[k];
    out[g] = o;
}

extern "C" void kernel_launch(void* const* d_in, const int* in_sizes, int n_in,
                              void* d_out, int out_size, void* d_ws, size_t ws_size,
                              hipStream_t stream) {
    const float* x   = (const float*)d_in[0];
    const int*   ei  = (const int*)d_in[1];
    const int*   src = ei;
    const int*   dst = ei + N_EDGES;
    const int*   batch = (const int*)d_in[2];
    const float* ea  = (const float*)d_in[3];
    const float* cw0 = (const float*)d_in[4];
    const float* cwr = (const float*)d_in[5];
    const float* cb  = (const float*)d_in[6];
    const float* lw  = (const float*)d_in[7];
    const float* lb  = (const float*)d_in[8];
    const float* w1  = (const float*)d_in[9];
    const float* b1  = (const float*)d_in[10];
    const float* w2  = (const float*)d_in[11];
    const float* b2  = (const float*)d_in[12];
    const float* w3  = (const float*)d_in[13];
    const float* b3  = (const float*)d_in[14];
    float* out = (float*)d_out;

    // workspace layout (4-byte units); bucketed is 8-byte aligned (offset 845076 even)
    float* ws      = (float*)d_ws;
    float* dinv    = ws;                                   // 200000
    int*   blkhist = (int*)(ws + 200000);                  // 782*782 = 611524
    int*   bstart  = blkhist + 611524;                     // 783 (pad 784)
    float* num     = (float*)(bstart + 784);               // 16384
    float* den     = num + 16384;                          // 16384
    unsigned long long* bucketed = (unsigned long long*)(den + 16384);  // E
    float* hW      = (float*)(bucketed + N_EDGES);         // 3.2M
    float* h       = hW + (size_t)N_NODES * HD;            // 3.2M

    hipMemsetAsync(num, 0, (size_t)2 * N_GRAPHS * HD * sizeof(float), stream);

    // bucket sort by dst>>8 (no global atomics anywhere)
    hist_kernel<<<NBLKA, 256, 0, stream>>>(dst, blkhist);
    scanA_kernel<<<NBUCK, 256, 0, stream>>>(blkhist, bstart);
    scanB_kernel<<<1, 256, 0, stream>>>(bstart);
    scatter_kernel<<<NBLKA, 256, 0, stream>>>(src, dst, ea, blkhist, bstart, bucketed);

    // degree -> dinv, then enorm rewrite in place
    dinvB_kernel<<<NBUCK, 256, 0, stream>>>(bucketed, bstart, dinv);
    wnorm_kernel<<<NBUCK, 256, 0, stream>>>(bucketed, bstart, dinv);

    // layer 0 (rank-1 fast path)
    agg0_kernel<<<NBUCK, 256, 0, stream>>>(bucketed, bstart, x, dinv, cw0, cb, lw, lb, h);
    // layers 1,2
    for (int l = 1; l < 3; ++l) {
        mat16_kernel<<<NBUCK, 256, 0, stream>>>(h, cwr + (l - 1) * 256, hW);
        agg_kernel<<<NBUCK, 256, 0, stream>>>(bucketed, bstart, hW, dinv,
                                              cb + l * 16, lw + l * 256, lb + l * 16, h);
    }

    pool_kernel<<<(N_NODES + 16 * POOL_RUN - 1) / (16 * POOL_RUN), 256, 0, stream>>>(h, batch, num, den);
    final_kernel<<<(N_GRAPHS + 63) / 64, 64, 0, stream>>>(num, den, w1, b1, w2, b2, w3, b3, out);
}

// Round 4
// 982.115 us; speedup vs baseline: 1.0448x; 1.0448x over previous
//
#include <hip/hip_runtime.h>

#define N_NODES 200000
#define N_EDGES 3200000
#define N_GRAPHS 1024
#define HD 16
#define ALPHA_ 0.2f

#define BNODES 256                 // nodes per bucket (dst >> 8)
#define NBUCK 782                  // ceil(N_NODES/256)
#define CHUNKA 4096                // edges per pass-A block
#define NBLKA 782                  // ceil(N_EDGES/CHUNKA)

typedef unsigned long long u64;

// ---------- bucket sort by dst>>8 (no global atomics) ----------
__global__ __launch_bounds__(256) void hist_kernel(const int* __restrict__ dst,
                                                   int* __restrict__ blkhist) {
    __shared__ int hist[NBUCK];
    int t = threadIdx.x;
    for (int i = t; i < NBUCK; i += 256) hist[i] = 0;
    __syncthreads();
    int e0 = blockIdx.x * CHUNKA;
    int e1 = min(e0 + CHUNKA, N_EDGES);
    for (int e = e0 + t; e < e1; e += 256)
        atomicAdd(&hist[dst[e] >> 8], 1);
    __syncthreads();
    int* out = blkhist + (size_t)blockIdx.x * NBUCK;
    for (int i = t; i < NBUCK; i += 256) out[i] = hist[i];
}

__global__ __launch_bounds__(256) void scanA_kernel(int* __restrict__ blkhist,
                                                    int* __restrict__ bstart) {
    __shared__ int s[256];
    int u = blockIdx.x, t = threadIdx.x;
    int v[4];
    int sum = 0;
#pragma unroll
    for (int i = 0; i < 4; ++i) {
        int j = t * 4 + i;
        v[i] = (j < NBLKA) ? blkhist[(size_t)j * NBUCK + u] : 0;
        sum += v[i];
    }
    s[t] = sum;
    __syncthreads();
    for (int off = 1; off < 256; off <<= 1) {
        int x = (t >= off) ? s[t - off] : 0;
        __syncthreads();
        s[t] += x;
        __syncthreads();
    }
    int run = s[t] - sum;
#pragma unroll
    for (int i = 0; i < 4; ++i) {
        int j = t * 4 + i;
        if (j < NBLKA) blkhist[(size_t)j * NBUCK + u] = run;
        run += v[i];
    }
    if (t == 255) bstart[u] = s[255];
}

__global__ __launch_bounds__(256) void scanB_kernel(int* __restrict__ bstart) {
    __shared__ int s[256];
    int t = threadIdx.x;
    int v[4];
    int sum = 0;
#pragma unroll
    for (int i = 0; i < 4; ++i) {
        int j = t * 4 + i;
        v[i] = (j < NBUCK) ? bstart[j] : 0;
        sum += v[i];
    }
    s[t] = sum;
    __syncthreads();
    for (int off = 1; off < 256; off <<= 1) {
        int x = (t >= off) ? s[t - off] : 0;
        __syncthreads();
        s[t] += x;
        __syncthreads();
    }
    int run = s[t] - sum;
#pragma unroll
    for (int i = 0; i < 4; ++i) {
        int j = t * 4 + i;
        if (j < NBUCK) bstart[j] = run;
        run += v[i];
    }
    if (t == 255) bstart[NBUCK] = s[255];
}

// entry = (ea:32 | dlow:8 | src:18)
__global__ __launch_bounds__(256) void scatter_kernel(const int* __restrict__ src,
                                                      const int* __restrict__ dst,
                                                      const float* __restrict__ ea,
                                                      const int* __restrict__ blkhist,
                                                      const int* __restrict__ bstart,
                                                      u64* __restrict__ bucketed) {
    __shared__ int cursor[NBUCK];
    int t = threadIdx.x;
    const int* bo = blkhist + (size_t)blockIdx.x * NBUCK;
    for (int i = t; i < NBUCK; i += 256) cursor[i] = bstart[i] + bo[i];
    __syncthreads();
    int e0 = blockIdx.x * CHUNKA;
    int e1 = min(e0 + CHUNKA, N_EDGES);
    for (int e = e0 + t; e < e1; e += 256) {
        int d = dst[e];
        int u = d >> 8;
        int pos = atomicAdd(&cursor[u], 1);   // LDS atomic
        u64 ent = ((u64)__float_as_uint(ea[e]) << 32)
                | (unsigned)(src[e] | ((d & 255) << 18));
        bucketed[pos] = ent;
    }
}

// weighted degree -> dinv[n] and dx[n] = {dinv, dinv*x}
__global__ __launch_bounds__(256) void dinvB_kernel(const u64* __restrict__ bucketed,
                                                    const int* __restrict__ bstart,
                                                    const float* __restrict__ x,
                                                    float* __restrict__ dinv,
                                                    float2* __restrict__ dx) {
    __shared__ float wdeg[BNODES];
    int u = blockIdx.x, t = threadIdx.x;
    wdeg[t] = 0.f;
    __syncthreads();
    int b0 = bstart[u], b1 = bstart[u + 1];
    for (int i = b0 + t; i < b1; i += 256) {
        u64 ent = bucketed[i];
        atomicAdd(&wdeg[(int)((ent >> 18) & 255u)], __uint_as_float((unsigned)(ent >> 32)));
    }
    __syncthreads();
    int n = u * BNODES + t;
    if (n < N_NODES) {
        float dn = rsqrtf(wdeg[t] + 1.0f);
        dinv[n] = dn;
        dx[n] = make_float2(dn, dn * x[n]);
    }
}

// layer 0 (rank-1): scalar agg via dx gather, rewrite ea->w in place,
// fused epilogue: relu(base*cw0+cb) @ lw0 + lb0, then @ cwr0 -> outw (= hW for layer 1)
__global__ __launch_bounds__(512, 6) void agg0_kernel(u64* __restrict__ bucketed,
                                                      const int* __restrict__ bstart,
                                                      const float2* __restrict__ dx,
                                                      const float* __restrict__ cw0,
                                                      const float* __restrict__ cb0,
                                                      const float* __restrict__ lw0,
                                                      const float* __restrict__ lb0,
                                                      const float* __restrict__ cwn,
                                                      float* __restrict__ outw) {
    __shared__ float acc[BNODES];
    __shared__ float sd[BNODES], sdy[BNODES];
    __shared__ float sW[256], sW2[256];
    __shared__ float scw[16], scb[16], slb[16];
    int u = blockIdx.x, t = threadIdx.x;
    if (t < 256) {
        sW[t] = lw0[t];
        sW2[t] = cwn[t];
        int n = u * BNODES + t;
        float2 d = (n < N_NODES) ? dx[n] : make_float2(0.f, 0.f);
        sd[t] = d.x;
        sdy[t] = d.y;
        acc[t] = 0.f;
    }
    if (t < 16) { scw[t] = cw0[t]; scb[t] = cb0[t]; slb[t] = lb0[t]; }
    __syncthreads();
    int b0 = bstart[u], b1 = bstart[u + 1];
    for (int i = b0 + (t << 2); i < b1; i += 2048) {
        u64 ent[4];
        float2 g[4];
#pragma unroll
        for (int k = 0; k < 4; ++k)
            if (i + k < b1) ent[k] = bucketed[i + k];
#pragma unroll
        for (int k = 0; k < 4; ++k)
            if (i + k < b1) g[k] = dx[(int)(ent[k] & 0x3ffffu)];
#pragma unroll
        for (int k = 0; k < 4; ++k)
            if (i + k < b1) {
                int dl = (int)((ent[k] >> 18) & 255u);
                float eav = __uint_as_float((unsigned)(ent[k] >> 32));
                float wd = eav * sd[dl];           // ea * dinv[d]
                float w = wd * g[k].x;             // full normalized weight
                bucketed[i + k] = ((u64)__float_as_uint(w) << 32)
                                | (unsigned)(ent[k] & 0x03ffffffu);
                atomicAdd(&acc[dl], wd * g[k].y);  // = w * x[s]
            }
    }
    __syncthreads();
    if (t >= 256) return;
    int n = u * BNODES + t;
    if (n >= N_NODES) return;
    float base = acc[t] + sd[t] * sdy[t];          // agg + dinv^2 * x[n]
    float a[16];
#pragma unroll
    for (int j = 0; j < 16; ++j) a[j] = fmaxf(base * scw[j] + scb[j], 0.f);
    float o[16];
#pragma unroll
    for (int j = 0; j < 16; ++j) o[j] = slb[j];
#pragma unroll
    for (int k = 0; k < 16; ++k)
#pragma unroll
        for (int j = 0; j < 16; ++j) o[j] += a[k] * sW[k * 16 + j];
    float o2[16];
#pragma unroll
    for (int j = 0; j < 16; ++j) o2[j] = 0.f;
#pragma unroll
    for (int k = 0; k < 16; ++k)
#pragma unroll
        for (int j = 0; j < 16; ++j) o2[j] += o[k] * sW2[k * 16 + j];
    float4* op = (float4*)(outw + (size_t)n * HD);
    op[0] = make_float4(o2[0], o2[1], o2[2], o2[3]);
    op[1] = make_float4(o2[4], o2[5], o2[6], o2[7]);
    op[2] = make_float4(o2[8], o2[9], o2[10], o2[11]);
    op[3] = make_float4(o2[12], o2[13], o2[14], o2[15]);
}

// layers 1,2: gather-agg with 4-deep batching; fused epilogue
// (relu(agg+self+cb) @ lw + lb) [@ cwn if fuse_next] -> outp
__global__ __launch_bounds__(512, 6) void agg_kernel(const u64* __restrict__ bucketed,
                                                     const int* __restrict__ bstart,
                                                     const float* __restrict__ hW,
                                                     const float* __restrict__ dinv,
                                                     const float* __restrict__ cb_l,
                                                     const float* __restrict__ lw_l,
                                                     const float* __restrict__ lb_l,
                                                     const float* __restrict__ cwn,
                                                     int fuse_next,
                                                     float* __restrict__ outp) {
    __shared__ float acc[BNODES * 16];   // 16 KB
    __shared__ float sW[256], sW2[256], sd[BNODES];
    __shared__ float scb[16], sb[16];
    int u = blockIdx.x, t = threadIdx.x;
    if (t < 256) {
        sW[t] = lw_l[t];
        sW2[t] = cwn[t];
        int n = u * BNODES + t;
        sd[t] = (n < N_NODES) ? dinv[n] : 0.f;
    }
    if (t < 16) { scb[t] = cb_l[t]; sb[t] = lb_l[t]; }
    for (int i = t; i < BNODES * 16; i += 512) acc[i] = 0.f;
    __syncthreads();
    int b0 = bstart[u], b1 = bstart[u + 1];
    int j = t & 15, es = t >> 4;   // 32 edge slots x 16 feature lanes
    for (int i = b0 + (es << 2); i < b1; i += 128) {
        u64 ent[4];
        float g[4];
#pragma unroll
        for (int k = 0; k < 4; ++k)
            if (i + k < b1) ent[k] = bucketed[i + k];
#pragma unroll
        for (int k = 0; k < 4; ++k)
            if (i + k < b1) g[k] = hW[(size_t)((int)(ent[k] & 0x3ffffu)) * 16 + j];
#pragma unroll
        for (int k = 0; k < 4; ++k)
            if (i + k < b1) {
                int dl = (int)((ent[k] >> 18) & 255u);
                float w = __uint_as_float((unsigned)(ent[k] >> 32));
                atomicAdd(&acc[dl * 16 + j], w * g[k]);
            }
    }
    __syncthreads();
    int bl = (t & 63) & ~15;
    for (int l0 = 0; l0 < BNODES; l0 += 32) {
        int l = l0 + (t >> 4);
        int n = u * BNODES + l;
        float selfw = (n < N_NODES) ? hW[(size_t)n * 16 + j] : 0.f;
        float a = fmaxf(acc[l * 16 + j] + sd[l] * sd[l] * selfw + scb[j], 0.f);
        float o = sb[j];
#pragma unroll
        for (int k = 0; k < 16; ++k) o += __shfl(a, bl + k, 64) * sW[k * 16 + j];
        if (fuse_next) {
            float o2 = 0.f;
#pragma unroll
            for (int k = 0; k < 16; ++k) o2 += __shfl(o, bl + k, 64) * sW2[k * 16 + j];
            o = o2;
        }
        if (n < N_NODES) outp[(size_t)n * 16 + j] = o;
    }
}

// segmented pooling over sorted batch
#define POOL_RUN 32
__global__ __launch_bounds__(256) void pool_kernel(const float* __restrict__ h,
                                                   const int* __restrict__ batch,
                                                   float* __restrict__ num,
                                                   float* __restrict__ den) {
    int t = threadIdx.x;
    int tg = t >> 4, j = t & 15;
    int n_start = blockIdx.x * (16 * POOL_RUN) + tg * POOL_RUN;
    float accn = 0.f, accd = 0.f;
    int cur = -1;
    for (int k = 0; k < POOL_RUN; ++k) {
        int n = n_start + k;
        if (n >= N_NODES) break;
        int g = batch[n];
        if (g != cur) {
            if (cur >= 0) {
                atomicAdd(&num[cur * HD + j], accn);
                atomicAdd(&den[cur * HD + j], accd);
            }
            cur = g;
            accn = 0.f;
            accd = 0.f;
        }
        float v = h[(size_t)n * HD + j];
        float s = expf(ALPHA_ * v);
        accn += v * s;
        accd += s;
    }
    if (cur >= 0) {
        atomicAdd(&num[cur * HD + j], accn);
        atomicAdd(&den[cur * HD + j], accd);
    }
}

__global__ __launch_bounds__(64) void final_kernel(const float* __restrict__ num,
                                                   const float* __restrict__ den,
                                                   const float* __restrict__ w1,
                                                   const float* __restrict__ b1,
                                                   const float* __restrict__ w2,
                                                   const float* __restrict__ b2,
                                                   const float* __restrict__ w3,
                                                   const float* __restrict__ b3,
                                                   float* __restrict__ out) {
    int g = blockIdx.x * blockDim.x + threadIdx.x;
    if (g >= N_GRAPHS) return;
    float p[16];
#pragma unroll
    for (int j = 0; j < 16; ++j) p[j] = num[g * HD + j] / den[g * HD + j];
    float t1[16];
#pragma unroll
    for (int j = 0; j < 16; ++j) {
        float acc = b1[j];
#pragma unroll
        for (int k = 0; k < 16; ++k) acc += p[k] * w1[k * 16 + j];
        t1[j] = fmaxf(acc, 0.f);
    }
    float t2[16];
#pragma unroll
    for (int j = 0; j < 16; ++j) {
        float acc = b2[j];
#pragma unroll
        for (int k = 0; k < 16; ++k) acc += t1[k] * w2[k * 16 + j];
        t2[j] = fmaxf(acc, 0.f);
    }
    float o = b3[0];
#pragma unroll
    for (int k = 0; k < 16; ++k) o += t2[k] * w3[k];
    out[g] = o;
}

extern "C" void kernel_launch(void* const* d_in, const int* in_sizes, int n_in,
                              void* d_out, int out_size, void* d_ws, size_t ws_size,
                              hipStream_t stream) {
    const float* x   = (const float*)d_in[0];
    const int*   ei  = (const int*)d_in[1];
    const int*   src = ei;
    const int*   dst = ei + N_EDGES;
    const int*   batch = (const int*)d_in[2];
    const float* ea  = (const float*)d_in[3];
    const float* cw0 = (const float*)d_in[4];
    const float* cwr = (const float*)d_in[5];
    const float* cb  = (const float*)d_in[6];
    const float* lw  = (const float*)d_in[7];
    const float* lb  = (const float*)d_in[8];
    const float* w1  = (const float*)d_in[9];
    const float* b1  = (const float*)d_in[10];
    const float* w2  = (const float*)d_in[11];
    const float* b2  = (const float*)d_in[12];
    const float* w3  = (const float*)d_in[13];
    const float* b3  = (const float*)d_in[14];
    float* out = (float*)d_out;

    // workspace layout (4-byte units); dx and bucketed 8-byte aligned
    float* ws      = (float*)d_ws;
    float* dinv    = ws;                                   // 200000
    int*   blkhist = (int*)(ws + 200000);                  // 611524
    int*   bstart  = blkhist + 611524;                     // 783 (pad 784)
    float* num     = (float*)(bstart + 784);               // 16384
    float* den     = num + 16384;                          // 16384
    float2* dx     = (float2*)(den + 16384);               // 200000 float2 (offset 845076, even)
    u64* bucketed  = (u64*)((float*)dx + 400000);          // E (offset 1245076, even)
    float* bufA    = (float*)(bucketed + N_EDGES);         // N*16
    float* bufB    = bufA + (size_t)N_NODES * HD;          // N*16

    hipMemsetAsync(num, 0, (size_t)2 * N_GRAPHS * HD * sizeof(float), stream);

    // bucket sort by dst>>8
    hist_kernel<<<NBLKA, 256, 0, stream>>>(dst, blkhist);
    scanA_kernel<<<NBUCK, 256, 0, stream>>>(blkhist, bstart);
    scanB_kernel<<<1, 256, 0, stream>>>(bstart);
    scatter_kernel<<<NBLKA, 256, 0, stream>>>(src, dst, ea, blkhist, bstart, bucketed);

    // degree -> dinv + dx
    dinvB_kernel<<<NBUCK, 256, 0, stream>>>(bucketed, bstart, x, dinv, dx);

    // layer 0: agg + weight rewrite + epilogue(+cwr0) -> bufA (= hW for layer 1)
    agg0_kernel<<<NBUCK, 512, 0, stream>>>(bucketed, bstart, dx, cw0, cb, lw, lb, cwr, bufA);
    // layer 1: read bufA, epilogue(+cwr1) -> bufB (= hW for layer 2)
    agg_kernel<<<NBUCK, 512, 0, stream>>>(bucketed, bstart, bufA, dinv,
                                          cb + 16, lw + 256, lb + 16, cwr + 256, 1, bufB);
    // layer 2: read bufB -> bufA (= final h)
    agg_kernel<<<NBUCK, 512, 0, stream>>>(bucketed, bstart, bufB, dinv,
                                          cb + 32, lw + 512, lb + 32, cwr, 0, bufA);

    pool_kernel<<<(N_NODES + 16 * POOL_RUN - 1) / (16 * POOL_RUN), 256, 0, stream>>>(bufA, batch, num, den);
    final_kernel<<<(N_GRAPHS + 63) / 64, 64, 0, stream>>>(num, den, w1, b1, w2, b2, w3, b3, out);
}